// Round 7
// baseline (217.981 us; speedup 1.0000x reference)
//
#include <hip/hip_runtime.h>

typedef __bf16 bf16x8 __attribute__((ext_vector_type(8)));
typedef __bf16 bf16x4 __attribute__((ext_vector_type(4)));
typedef float  f32x4  __attribute__((ext_vector_type(4)));

#define P_  2048
#define D_  4096
#define IC_ 512
#define H_  256
#define R_  5
#define KP_ (R_*D_)   /* 20480 : K for z_p  (r,d) */
#define KD_ (R_*P_)   /* 10240 : K for z_d  (r,p) */

// BK=64 swizzle: slot' = slot ^ swz8(row), slots span 8x16B = full 128B row.
// 8-lane-group analysis: frag ds_read_b128 (16 consecutive rows, fixed slot),
// A ds_write_b128 (8 lanes share row, slots 0-7), zd b16 scatter (rows 8 apart)
// all map each 8-lane group to 8 distinct 16B bank-groups -> conflict-free.
__device__ __forceinline__ int swz8(int row){ return (row ^ (row>>3)) & 7; }
// legacy BK=32 swizzle for k_tmp (validated r2-r6)
__device__ __forceinline__ int swzf(int row){ return ((row>>1) ^ (row>>3)) & 3; }

__device__ __forceinline__ bf16x8 cvt8(float4 a, float4 b){
  bf16x8 o;
  o[0]=(__bf16)a.x; o[1]=(__bf16)a.y; o[2]=(__bf16)a.z; o[3]=(__bf16)a.w;
  o[4]=(__bf16)b.x; o[5]=(__bf16)b.y; o[6]=(__bf16)b.z; o[7]=(__bf16)b.w;
  return o;
}

__device__ __forceinline__ void gl_lds16(const __bf16* g, __bf16* l){
  __builtin_amdgcn_global_load_lds(
    (const __attribute__((address_space(1))) unsigned int*)(g),
    (__attribute__((address_space(3))) unsigned int*)(l), 16, 0, 0);
}

// ---------------- K1: fused wcum + prep. blocks [0,320): prep slab; [320,384): wcum ----------------
__global__ __launch_bounds__(256) void k_prep2(const float* __restrict__ S,
    const float* __restrict__ pw, __bf16* __restrict__ Sbf, float* __restrict__ rs,
    float* __restrict__ cspart, __bf16* __restrict__ wct){
  __shared__ float wsum[32][4];
  const int t = threadIdx.x;
  if (blockIdx.x >= 320){
    const int h  = t;
    const int i0 = (blockIdx.x - 320) * 8;
    float acc[8];
    #pragma unroll
    for (int j=0;j<8;++j) acc[j]=0.f;
    for (int r=0;r<R_;++r){
      bf16x8 o;
      #pragma unroll
      for (int j=0;j<8;++j){
        acc[j] += pw[((size_t)r*IC_ + i0 + j)*H_ + h];
        o[j] = (__bf16)acc[j];
      }
      *reinterpret_cast<bf16x8*>(wct + ((size_t)r*H_ + h)*IC_ + i0) = o;
    }
    return;
  }
  const int lane = t & 63, w = t >> 6;
  const int slab = blockIdx.x;
  const int r = slab >> 6, z = slab & 63;
  const size_t row0 = (size_t)r*P_ + (size_t)z*32;
  const float4* src = reinterpret_cast<const float4*>(S + row0*D_);
  __bf16* dst = Sbf + row0*D_;
  f32x4 ca[4];
  #pragma unroll
  for (int c=0;c<4;++c){ ca[c][0]=0.f; ca[c][1]=0.f; ca[c][2]=0.f; ca[c][3]=0.f; }
  for (int pp=0; pp<32; ++pp){
    float4 v[4];
    #pragma unroll
    for (int c=0;c<4;++c) v[c] = src[(size_t)pp*(D_/4) + t + 256*c];
    float rsum = 0.f;
    #pragma unroll
    for (int c=0;c<4;++c){
      ca[c][0]+=v[c].x; ca[c][1]+=v[c].y; ca[c][2]+=v[c].z; ca[c][3]+=v[c].w;
      rsum += v[c].x+v[c].y+v[c].z+v[c].w;
      bf16x4 o; o[0]=(__bf16)v[c].x; o[1]=(__bf16)v[c].y; o[2]=(__bf16)v[c].z; o[3]=(__bf16)v[c].w;
      *reinterpret_cast<bf16x4*>(dst + (size_t)pp*D_ + (t + 256*c)*4) = o;
    }
    #pragma unroll
    for (int off = 32; off; off >>= 1) rsum += __shfl_xor(rsum, off);
    if (lane == 0) wsum[pp][w] = rsum;
  }
  __syncthreads();
  if (t < 32){
    float s = wsum[t][0]+wsum[t][1]+wsum[t][2]+wsum[t][3];
    rs[row0 + t] = (s > 0.f) ? rsqrtf(s) : 0.f;
  }
  float* o = cspart + ((size_t)z*R_ + r)*D_;
  #pragma unroll
  for (int c=0;c<4;++c) *reinterpret_cast<f32x4*>(o + (t + 256*c)*4) = ca[c];
}

__global__ void k_csfin(const float* __restrict__ cspart, float* __restrict__ cs){
  const int i = blockIdx.x*256 + threadIdx.x;
  float s = 0.f;
  #pragma unroll
  for (int z = 0; z < 64; ++z) s += cspart[(size_t)z*(R_*D_) + i];
  cs[i] = (s > 0.f) ? rsqrtf(s) : 0.f;
}

// ---------------- K5: merged tmp GEMMs (r4 2-barrier form — validated) ----------------
__global__ __launch_bounds__(256) void k_tmp(const float* __restrict__ p_feat,
    const float* __restrict__ d_feat, const float* __restrict__ rs,
    const float* __restrict__ cs, const __bf16* __restrict__ wct,
    __bf16* __restrict__ Tpt, __bf16* __restrict__ Tdt){
  __shared__ __bf16 As[64*40];
  const int t = threadIdx.x, lane = t & 63, w = t >> 6;
  const int mt = blockIdx.x, r = blockIdx.y;
  const bool isp = mt < (P_/64);
  const float* feat  = isp ? p_feat : d_feat;
  const float* scale = isp ? rs : cs;
  __bf16* outT = isp ? Tpt : Tdt;
  const int M  = isp ? P_ : D_;
  const int RM = isp ? KD_ : KP_;
  const int m0 = (isp ? mt : mt - P_/64)*64;
  const int srow = t >> 2, skc = (t & 3)*8;
  f32x4 acc[4][4];
  #pragma unroll
  for (int a=0;a<4;++a)
    #pragma unroll
    for (int b=0;b<4;++b){ acc[a][b][0]=0.f; acc[a][b][1]=0.f; acc[a][b][2]=0.f; acc[a][b][3]=0.f; }

  for (int ks = 0; ks < IC_; ks += 32){
    __syncthreads();
    {
      const float* g = feat + (size_t)(m0+srow)*IC_ + ks + skc;
      float4 a = *(const float4*)g, b = *(const float4*)(g+4);
      *reinterpret_cast<bf16x8*>(&As[srow*40 + skc]) = cvt8(a,b);
    }
    __syncthreads();
    bf16x8 af[4], bfv[4];
    #pragma unroll
    for (int tt=0;tt<4;++tt)
      af[tt] = *reinterpret_cast<const bf16x8*>(&As[(16*tt + (lane&15))*40 + (lane>>4)*8]);
    #pragma unroll
    for (int cc=0;cc<4;++cc)
      bfv[cc] = *reinterpret_cast<const bf16x8*>(wct + ((size_t)r*H_ + w*64 + 16*cc + (lane&15))*IC_ + ks + (lane>>4)*8);
    #pragma unroll
    for (int tt=0;tt<4;++tt)
      #pragma unroll
      for (int cc=0;cc<4;++cc)
        acc[tt][cc] = __builtin_amdgcn_mfma_f32_16x16x32_bf16(af[tt], bfv[cc], acc[tt][cc], 0, 0, 0);
  }
  #pragma unroll
  for (int tt=0;tt<4;++tt){
    const int mb = m0 + 16*tt + ((lane>>4)<<2);
    const float s0 = scale[r*M+mb+0], s1 = scale[r*M+mb+1],
                s2 = scale[r*M+mb+2], s3 = scale[r*M+mb+3];
    #pragma unroll
    for (int cc=0;cc<4;++cc){
      const int hc = (w<<6) + 16*cc + (lane&15);
      bf16x4 v;
      v[0]=(__bf16)(acc[tt][cc][0]*s0); v[1]=(__bf16)(acc[tt][cc][1]*s1);
      v[2]=(__bf16)(acc[tt][cc][2]*s2); v[3]=(__bf16)(acc[tt][cc][3]*s3);
      *reinterpret_cast<bf16x4*>(outT + (size_t)hc*RM + r*M + mb) = v;
    }
  }
}

// ---------------- K6: merged z GEMM, BK=64, balanced 512 grid, scale-in-staging ----------------
// blocks [0,256): zp (16 tiles x 16 splits); [256,512): zd (32 tiles x 8 splits).
// chunk=1280 -> 20 iters of BK=64 each; exactly 2 blocks/CU. LDS 48KB.
__global__ __launch_bounds__(512, 4) void k_z(const __bf16* __restrict__ Sbf,
    const float* __restrict__ rs, const float* __restrict__ cs,
    const __bf16* __restrict__ Tdt, const __bf16* __restrict__ Tpt,
    float* __restrict__ partP, float* __restrict__ partD){
  __shared__ __bf16 As[128*64];   // 16 KB
  __shared__ __bf16 Bs[256*64];   // 32 KB
  const int t = threadIdx.x, lane = t & 63, w = t >> 6;
  const int wm = w >> 2, wn = w & 3;
  const int bid = blockIdx.x;
  const bool isp = bid < 256;
  const int tile  = isp ? (bid & 15) : ((bid-256) & 31);
  const int split = isp ? (bid >> 4) : ((bid-256) >> 5);
  const int m0 = tile*128;
  const int kbase = split*1280;
  const __bf16* Bsrc = isp ? Tdt : Tpt;
  const int bstr = isp ? KP_ : KD_;
  // staging indices
  const int srow = t >> 3, sslot = t & 7;        // zp A rows (2 passes), B rows (4 passes)
  const int krow0 = t >> 4, d8 = (t & 15)*8;     // zd transpose
  f32x4 acc[4][4];
  #pragma unroll
  for (int a=0;a<4;++a)
    #pragma unroll
    for (int b=0;b<4;++b){ acc[a][b][0]=0.f; acc[a][b][1]=0.f; acc[a][b][2]=0.f; acc[a][b][3]=0.f; }

  for (int ko = 0; ko < 1280; ko += 64){
    const int kg = kbase + ko;                   // 64-step never straddles r (4096/2048 % 64 == 0)
    __syncthreads();
    if (isp){
      const int r = kg >> 12, dd = kg & (D_-1);
      #pragma unroll
      for (int q=0;q<2;++q){
        const int row = q*64 + srow;
        const float sc = rs[r*P_ + m0 + row];
        bf16x8 v = *reinterpret_cast<const bf16x8*>(Sbf + ((size_t)r*P_ + m0 + row)*D_ + dd + sslot*8);
        bf16x8 o;
        #pragma unroll
        for (int j=0;j<8;++j) o[j] = (__bf16)((float)v[j] * sc);
        *reinterpret_cast<bf16x8*>(&As[row*64 + ((sslot ^ swz8(row))<<3)]) = o;
      }
    } else {
      const int r = kg >> 11, pp = kg & (P_-1);
      const float4 c1 = *(const float4*)(cs + r*D_ + m0 + d8);
      const float4 c2 = *(const float4*)(cs + r*D_ + m0 + d8 + 4);
      float cf[8] = {c1.x,c1.y,c1.z,c1.w,c2.x,c2.y,c2.z,c2.w};
      #pragma unroll
      for (int q=0;q<2;++q){
        const int kr = q*32 + krow0;
        bf16x8 va = *reinterpret_cast<const bf16x8*>(Sbf + ((size_t)r*P_ + pp + kr)*D_ + m0 + d8);
        const int slot = kr >> 3, kb = kr & 7;
        #pragma unroll
        for (int j=0;j<8;++j){
          const int rowd = d8 + j;
          As[rowd*64 + ((slot ^ swz8(rowd))<<3) + kb] = (__bf16)((float)va[j] * cf[j]);
        }
      }
    }
    #pragma unroll
    for (int q=0;q<4;++q){
      const int row = q*64 + srow;
      gl_lds16(Bsrc + (size_t)row*bstr + kg + ((sslot ^ swz8(row))<<3), Bs + q*4096 + w*512);
    }
    __syncthreads();
    const int kq = lane >> 4;
    #pragma unroll
    for (int ksub=0; ksub<2; ++ksub){
      const int s = ksub*4 + kq;
      bf16x8 bv[4];
      #pragma unroll
      for (int cc=0;cc<4;++cc){
        const int row = wn*64 + 16*cc + (lane&15);
        bv[cc] = *reinterpret_cast<const bf16x8*>(&Bs[row*64 + ((s ^ swz8(row))<<3)]);
      }
      #pragma unroll
      for (int tt=0;tt<4;++tt){
        const int row = wm*64 + 16*tt + (lane&15);
        bf16x8 af = *reinterpret_cast<const bf16x8*>(&As[row*64 + ((s ^ swz8(row))<<3)]);
        #pragma unroll
        for (int cc=0;cc<4;++cc)
          acc[tt][cc] = __builtin_amdgcn_mfma_f32_16x16x32_bf16(af, bv[cc], acc[tt][cc], 0, 0, 0);
      }
    }
  }
  float* o = isp ? (partP + (size_t)split*((size_t)P_*H_))
                 : (partD + (size_t)split*((size_t)D_*H_));
  #pragma unroll
  for (int tt=0;tt<4;++tt){
    const int mb = m0 + wm*64 + 16*tt + ((lane>>4)<<2);
    #pragma unroll
    for (int cc=0;cc<4;++cc){
      const int hc = wn*64 + 16*cc + (lane&15);
      #pragma unroll
      for (int j=0;j<4;++j) o[(size_t)(mb+j)*H_ + hc] = acc[tt][cc][j];
    }
  }
}

// ---------------- K7: merged reduce + bias + LeakyReLU over both outputs ----------------
__global__ void k_reduce(const float* __restrict__ partP, const float* __restrict__ partD,
    const float* __restrict__ bias, float* __restrict__ out){
  const int i = (blockIdx.x*256 + threadIdx.x)*4;
  float4 s; s.x=s.y=s.z=s.w=0.f;
  if (i < P_*H_){
    #pragma unroll
    for (int z = 0; z < 16; ++z){
      float4 v = *(const float4*)(partP + (size_t)z*((size_t)P_*H_) + i);
      s.x+=v.x; s.y+=v.y; s.z+=v.z; s.w+=v.w;
    }
  } else {
    const int j = i - P_*H_;
    #pragma unroll
    for (int z = 0; z < 8; ++z){
      float4 v = *(const float4*)(partD + (size_t)z*((size_t)D_*H_) + j);
      s.x+=v.x; s.y+=v.y; s.z+=v.z; s.w+=v.w;
    }
  }
  const float4 b = *(const float4*)(bias + (i & (H_-1)));
  s.x+=b.x; s.y+=b.y; s.z+=b.z; s.w+=b.w;
  s.x = (s.x>=0.f)? s.x : 0.1f*s.x;
  s.y = (s.y>=0.f)? s.y : 0.1f*s.y;
  s.z = (s.z>=0.f)? s.z : 0.1f*s.z;
  s.w = (s.w>=0.f)? s.w : 0.1f*s.w;
  *(float4*)(out + i) = s;
}

extern "C" void kernel_launch(void* const* d_in, const int* in_sizes, int n_in,
                              void* d_out, int out_size, void* d_ws, size_t ws_size,
                              hipStream_t stream){
  (void)in_sizes; (void)n_in; (void)out_size; (void)ws_size;
  const float* p_feat = (const float*)d_in[0];
  const float* d_feat = (const float*)d_in[1];
  const float* S      = (const float*)d_in[4];
  const float* pw     = (const float*)d_in[5];
  const float* bias   = (const float*)d_in[6];
  float* out = (float*)d_out;

  char* ws = (char*)d_ws;
  __bf16* wct    = (__bf16*)(ws + 0);           //  1,310,720
  __bf16* Tdt    = (__bf16*)(ws + 1310720);     // 10,485,760
  __bf16* Tpt    = (__bf16*)(ws + 11796480);    //  5,242,880
  float*  rs     = (float*) (ws + 17039360);    //     40,960
  float*  cs     = (float*) (ws + 17080320);    //     81,920
  float*  cspart = (float*) (ws + 17162240);    //  5,242,880 (64 slices)
  __bf16* Sbf    = (__bf16*)(ws + 22405120);    // 83,886,080
  float*  partP  = (float*) (ws + 106291200);   // 33,554,432 (16 slices)
  float*  partD  = (float*) (ws + 139845632);   // 33,554,432 (8 slices)
                                                // end: 173,400,064

  k_prep2 <<<384, 256, 0, stream>>>(S, pw, Sbf, rs, cspart, wct);
  k_csfin <<<(R_*D_)/256, 256, 0, stream>>>(cspart, cs);
  k_tmp   <<<dim3((P_+D_)/64, R_), 256, 0, stream>>>(p_feat, d_feat, rs, cs, wct, Tpt, Tdt);
  k_z     <<<512, 512, 0, stream>>>(Sbf, rs, cs, Tdt, Tpt, partP, partD);
  k_reduce<<<((P_+D_)*H_)/1024, 256, 0, stream>>>(partP, partD, bias, out);
}

// Round 8
// 211.175 us; speedup vs baseline: 1.0322x; 1.0322x over previous
//
#include <hip/hip_runtime.h>

typedef __bf16 bf16x8 __attribute__((ext_vector_type(8)));
typedef __bf16 bf16x4 __attribute__((ext_vector_type(4)));
typedef float  f32x4  __attribute__((ext_vector_type(4)));

#define P_  2048
#define D_  4096
#define IC_ 512
#define H_  256
#define R_  5
#define KP_ (R_*D_)   /* 20480 : K for z_p  (r,d) */
#define KD_ (R_*P_)   /* 10240 : K for z_d  (r,p) */

// LDS k-slot swizzle (validated r2-r4): frag ds_read_b128 / A ds_write_b128 -> free;
// zd transpose b16 scatter -> ~8-lane residual (known, next lever).
__device__ __forceinline__ int swzf(int row){ return ((row>>1) ^ (row>>3)) & 3; }

__device__ __forceinline__ bf16x8 cvt8(float4 a, float4 b){
  bf16x8 o;
  o[0]=(__bf16)a.x; o[1]=(__bf16)a.y; o[2]=(__bf16)a.z; o[3]=(__bf16)a.w;
  o[4]=(__bf16)b.x; o[5]=(__bf16)b.y; o[6]=(__bf16)b.z; o[7]=(__bf16)b.w;
  return o;
}

__device__ __forceinline__ void gl_lds16(const __bf16* g, __bf16* l){
  __builtin_amdgcn_global_load_lds(
    (const __attribute__((address_space(1))) unsigned int*)(g),
    (__attribute__((address_space(3))) unsigned int*)(l), 16, 0, 0);
}

// ---------------- K1: fused wcum + prep. blocks [0,320): prep slab; [320,384): wcum ----------------
__global__ __launch_bounds__(256) void k_prep2(const float* __restrict__ S,
    const float* __restrict__ pw, __bf16* __restrict__ Sbf, float* __restrict__ rs,
    float* __restrict__ cspart, __bf16* __restrict__ wct){
  __shared__ float wsum[32][4];
  const int t = threadIdx.x;
  if (blockIdx.x >= 320){
    const int h  = t;
    const int i0 = (blockIdx.x - 320) * 8;
    float acc[8];
    #pragma unroll
    for (int j=0;j<8;++j) acc[j]=0.f;
    for (int r=0;r<R_;++r){
      bf16x8 o;
      #pragma unroll
      for (int j=0;j<8;++j){
        acc[j] += pw[((size_t)r*IC_ + i0 + j)*H_ + h];
        o[j] = (__bf16)acc[j];
      }
      *reinterpret_cast<bf16x8*>(wct + ((size_t)r*H_ + h)*IC_ + i0) = o;
    }
    return;
  }
  const int lane = t & 63, w = t >> 6;
  const int slab = blockIdx.x;
  const int r = slab >> 6, z = slab & 63;
  const size_t row0 = (size_t)r*P_ + (size_t)z*32;
  const float4* src = reinterpret_cast<const float4*>(S + row0*D_);
  __bf16* dst = Sbf + row0*D_;
  f32x4 ca[4];
  #pragma unroll
  for (int c=0;c<4;++c){ ca[c][0]=0.f; ca[c][1]=0.f; ca[c][2]=0.f; ca[c][3]=0.f; }
  for (int pp=0; pp<32; ++pp){
    float4 v[4];
    #pragma unroll
    for (int c=0;c<4;++c) v[c] = src[(size_t)pp*(D_/4) + t + 256*c];
    float rsum = 0.f;
    #pragma unroll
    for (int c=0;c<4;++c){
      ca[c][0]+=v[c].x; ca[c][1]+=v[c].y; ca[c][2]+=v[c].z; ca[c][3]+=v[c].w;
      rsum += v[c].x+v[c].y+v[c].z+v[c].w;
      bf16x4 o; o[0]=(__bf16)v[c].x; o[1]=(__bf16)v[c].y; o[2]=(__bf16)v[c].z; o[3]=(__bf16)v[c].w;
      *reinterpret_cast<bf16x4*>(dst + (size_t)pp*D_ + (t + 256*c)*4) = o;
    }
    #pragma unroll
    for (int off = 32; off; off >>= 1) rsum += __shfl_xor(rsum, off);
    if (lane == 0) wsum[pp][w] = rsum;
  }
  __syncthreads();
  if (t < 32){
    float s = wsum[t][0]+wsum[t][1]+wsum[t][2]+wsum[t][3];
    rs[row0 + t] = (s > 0.f) ? rsqrtf(s) : 0.f;
  }
  float* o = cspart + ((size_t)z*R_ + r)*D_;
  #pragma unroll
  for (int c=0;c<4;++c) *reinterpret_cast<f32x4*>(o + (t + 256*c)*4) = ca[c];
}

__global__ void k_csfin(const float* __restrict__ cspart, float* __restrict__ cs){
  const int i = blockIdx.x*256 + threadIdx.x;
  float s = 0.f;
  #pragma unroll
  for (int z = 0; z < 64; ++z) s += cspart[(size_t)z*(R_*D_) + i];
  cs[i] = (s > 0.f) ? rsqrtf(s) : 0.f;
}

// ---------------- K5: merged tmp GEMMs (r4 2-barrier form — validated) ----------------
__global__ __launch_bounds__(256) void k_tmp(const float* __restrict__ p_feat,
    const float* __restrict__ d_feat, const float* __restrict__ rs,
    const float* __restrict__ cs, const __bf16* __restrict__ wct,
    __bf16* __restrict__ Tpt, __bf16* __restrict__ Tdt){
  __shared__ __bf16 As[64*40];
  const int t = threadIdx.x, lane = t & 63, w = t >> 6;
  const int mt = blockIdx.x, r = blockIdx.y;
  const bool isp = mt < (P_/64);
  const float* feat  = isp ? p_feat : d_feat;
  const float* scale = isp ? rs : cs;
  __bf16* outT = isp ? Tpt : Tdt;
  const int M  = isp ? P_ : D_;
  const int RM = isp ? KD_ : KP_;
  const int m0 = (isp ? mt : mt - P_/64)*64;
  const int srow = t >> 2, skc = (t & 3)*8;
  f32x4 acc[4][4];
  #pragma unroll
  for (int a=0;a<4;++a)
    #pragma unroll
    for (int b=0;b<4;++b){ acc[a][b][0]=0.f; acc[a][b][1]=0.f; acc[a][b][2]=0.f; acc[a][b][3]=0.f; }

  for (int ks = 0; ks < IC_; ks += 32){
    __syncthreads();
    {
      const float* g = feat + (size_t)(m0+srow)*IC_ + ks + skc;
      float4 a = *(const float4*)g, b = *(const float4*)(g+4);
      *reinterpret_cast<bf16x8*>(&As[srow*40 + skc]) = cvt8(a,b);
    }
    __syncthreads();
    bf16x8 af[4], bfv[4];
    #pragma unroll
    for (int tt=0;tt<4;++tt)
      af[tt] = *reinterpret_cast<const bf16x8*>(&As[(16*tt + (lane&15))*40 + (lane>>4)*8]);
    #pragma unroll
    for (int cc=0;cc<4;++cc)
      bfv[cc] = *reinterpret_cast<const bf16x8*>(wct + ((size_t)r*H_ + w*64 + 16*cc + (lane&15))*IC_ + ks + (lane>>4)*8);
    #pragma unroll
    for (int tt=0;tt<4;++tt)
      #pragma unroll
      for (int cc=0;cc<4;++cc)
        acc[tt][cc] = __builtin_amdgcn_mfma_f32_16x16x32_bf16(af[tt], bfv[cc], acc[tt][cc], 0, 0, 0);
  }
  #pragma unroll
  for (int tt=0;tt<4;++tt){
    const int mb = m0 + 16*tt + ((lane>>4)<<2);
    const float s0 = scale[r*M+mb+0], s1 = scale[r*M+mb+1],
                s2 = scale[r*M+mb+2], s3 = scale[r*M+mb+3];
    #pragma unroll
    for (int cc=0;cc<4;++cc){
      const int hc = (w<<6) + 16*cc + (lane&15);
      bf16x4 v;
      v[0]=(__bf16)(acc[tt][cc][0]*s0); v[1]=(__bf16)(acc[tt][cc][1]*s1);
      v[2]=(__bf16)(acc[tt][cc][2]*s2); v[3]=(__bf16)(acc[tt][cc][3]*s3);
      *reinterpret_cast<bf16x4*>(outT + (size_t)hc*RM + r*M + mb) = v;
    }
  }
}

// ---------------- K6: merged z GEMM, r4 structure + T4 counted-vmcnt pipeline ----------------
// 512 blocks: [0,256)=zp (16 tiles x 16 splits), [256,512)=zd (32 tiles x 8 splits);
// chunk=1280, 40 iters of BK=32; 2 blocks/CU; LDS 2x24KB double buffer.
// Slot after compute issues [regA(1), glB(2)] for tile i+2; top-of-iter waits
// exactly vmcnt(3) (B_i landed; A_{i+2}+B_{i+1} stay in flight). Raw s_barrier.
#define KG_(j) (kbase + 32*(j))
#define LOADA_(j, dst) { const int kg_ = KG_(j); \
  if (isp){ const int r_ = kg_>>12, dd_ = kg_&(D_-1); \
    dst = *reinterpret_cast<const bf16x8*>(Sbf + ((size_t)r_*P_ + m0 + arow)*D_ + dd_ + (t&3)*8); } \
  else { const int r_ = kg_>>11, pp_ = kg_&(P_-1); \
    dst = *reinterpret_cast<const bf16x8*>(Sbf + ((size_t)r_*P_ + pp_ + prow)*D_ + m0 + d8); } }

#define WRITEA_(j, va, Ab) { const int kg_ = KG_(j); \
  if (isp){ const int r_ = kg_>>12; const float sc_ = (r_==rA) ? scA : scB; \
    bf16x8 o_; \
    _Pragma("unroll") for (int jj=0;jj<8;++jj) o_[jj] = (__bf16)((float)va[jj]*sc_); \
    *reinterpret_cast<bf16x8*>(&(Ab)[arow*32 + aslot*8]) = o_; } \
  else { const int r_ = kg_>>11; const bool uA_ = (r_==rA); \
    _Pragma("unroll") for (int jj=0;jj<8;++jj){ const int rowd_ = d8 + jj; \
      (Ab)[rowd_*32 + ((kqw ^ swzf(rowd_))<<3) + koff] = (__bf16)((float)va[jj]*(uA_?cAf[jj]:cBf[jj])); } } }

#define ISSUEB_(j, Bb) { const int kg_ = KG_(j); \
  gl_lds16(Bsrc + (size_t)brow0*bstr + kg_ + bko0, (Bb) + w*512); \
  gl_lds16(Bsrc + (size_t)brow1*bstr + kg_ + bko1, (Bb) + 4096 + w*512); }

__global__ __launch_bounds__(512, 4) void k_z(const __bf16* __restrict__ Sbf,
    const float* __restrict__ rs, const float* __restrict__ cs,
    const __bf16* __restrict__ Tdt, const __bf16* __restrict__ Tpt,
    float* __restrict__ partP, float* __restrict__ partD){
  __shared__ __bf16 As[2][128*32];
  __shared__ __bf16 Bs[2][256*32];
  const int t = threadIdx.x, lane = t & 63, w = t >> 6;
  const int wm = w >> 2, wn = w & 3;
  const int bid = blockIdx.x;
  const bool isp = bid < 256;
  const int tile  = isp ? (bid & 15) : ((bid-256) & 31);
  const int split = isp ? (bid >> 4) : ((bid-256) >> 5);
  const int m0 = tile*128;
  const int kbase = split*1280;
  const __bf16* Bsrc = isp ? Tdt : Tpt;
  const int bstr = isp ? KP_ : KD_;
  // zp A-staging indices
  const int arow  = t >> 2;
  const int aslot = (t & 3) ^ swzf(arow);
  // zd A-staging indices
  const int prow = t >> 4, d8 = (t & 15)*8;
  const int kqw = prow >> 3, koff = prow & 7;
  // B-staging (linear gl_lds dest + inverse-swizzled global source)
  const int brow0 = t >> 2, brow1 = 128 + brow0;
  const int bko0 = ((t & 3) ^ swzf(brow0)) * 8;
  const int bko1 = ((t & 3) ^ swzf(brow1)) * 8;

  // preload per-r scales (a 1280-chunk spans at most 2 r's) -> zero per-iter VMEM in WRITEA_
  const int rA = isp ? (kbase >> 12) : (kbase >> 11);
  const int rB = isp ? ((kbase+1279) >> 12) : ((kbase+1279) >> 11);
  float scA = 0.f, scB = 0.f;
  float cAf[8], cBf[8];
  if (isp){
    scA = rs[rA*P_ + m0 + arow];
    scB = rs[rB*P_ + m0 + arow];
  } else {
    float4 a1 = *(const float4*)(cs + rA*D_ + m0 + d8);
    float4 a2 = *(const float4*)(cs + rA*D_ + m0 + d8 + 4);
    float4 b1 = *(const float4*)(cs + rB*D_ + m0 + d8);
    float4 b2 = *(const float4*)(cs + rB*D_ + m0 + d8 + 4);
    cAf[0]=a1.x; cAf[1]=a1.y; cAf[2]=a1.z; cAf[3]=a1.w;
    cAf[4]=a2.x; cAf[5]=a2.y; cAf[6]=a2.z; cAf[7]=a2.w;
    cBf[0]=b1.x; cBf[1]=b1.y; cBf[2]=b1.z; cBf[3]=b1.w;
    cBf[4]=b2.x; cBf[5]=b2.y; cBf[6]=b2.z; cBf[7]=b2.w;
  }

  f32x4 acc[4][4];
  #pragma unroll
  for (int a=0;a<4;++a)
    #pragma unroll
    for (int b=0;b<4;++b){ acc[a][b][0]=0.f; acc[a][b][1]=0.f; acc[a][b][2]=0.f; acc[a][b][3]=0.f; }

  // ---- prologue: stage tiles 0,1; preload regA for tile 2 ----
  {
    bf16x8 v0, v1;
    LOADA_(0, v0);
    LOADA_(1, v1);
    WRITEA_(0, v0, As[0]);
    ISSUEB_(0, Bs[0]);
    WRITEA_(1, v1, As[1]);
    ISSUEB_(1, Bs[1]);
  }
  bf16x8 vhold;
  LOADA_(2, vhold);

  for (int i = 0; i < 40; ++i){
    __bf16* Ac = As[i & 1];
    __bf16* Bc = Bs[i & 1];
    // wait: tile i's B gl_lds landed (drains exactly the 2 oldest + prior A-reg
    // consumed); slot's ds_writes drained; then all-wave rendezvous.
    asm volatile("s_waitcnt vmcnt(3) lgkmcnt(0)" ::: "memory");
    __builtin_amdgcn_s_barrier();
    __builtin_amdgcn_sched_barrier(0);
    // ---- compute on buffer i&1 (r4-exact) ----
    const int kq = lane >> 4;
    bf16x8 bv[4];
    #pragma unroll
    for (int cc=0;cc<4;++cc){
      const int row = wn*64 + 16*cc + (lane&15);
      bv[cc] = *reinterpret_cast<const bf16x8*>(&Bc[row*32 + ((kq ^ swzf(row))<<3)]);
    }
    #pragma unroll
    for (int tt=0;tt<4;++tt){
      const int row = wm*64 + 16*tt + (lane&15);
      bf16x8 af = *reinterpret_cast<const bf16x8*>(&Ac[row*32 + ((kq ^ swzf(row))<<3)]);
      #pragma unroll
      for (int cc=0;cc<4;++cc)
        acc[tt][cc] = __builtin_amdgcn_mfma_f32_16x16x32_bf16(af, bv[cc], acc[tt][cc], 0, 0, 0);
    }
    __builtin_amdgcn_sched_barrier(0);
    __builtin_amdgcn_s_barrier();   // all waves done reading buffer i&1
    // ---- slot: stage tile i+2 into buffer i&1 (clamped; redundant tail is unread) ----
    const int j2 = (i+2 > 39) ? 39 : (i+2);
    const int j3 = (i+3 > 39) ? 39 : (i+3);
    bf16x8 vtmp;
    LOADA_(j3, vtmp);        // issue first: keeps it "newer" than vhold in vmcnt order
    WRITEA_(j2, vhold, Ac);  // compiler waits vhold only (vmcnt(3): B_{i+1}+vtmp in flight)
    ISSUEB_(j2, Bc);
    vhold = vtmp;
  }

  float* o = isp ? (partP + (size_t)split*((size_t)P_*H_))
                 : (partD + (size_t)split*((size_t)D_*H_));
  #pragma unroll
  for (int tt=0;tt<4;++tt){
    const int mb = m0 + wm*64 + 16*tt + ((lane>>4)<<2);
    #pragma unroll
    for (int cc=0;cc<4;++cc){
      const int hc = wn*64 + 16*cc + (lane&15);
      #pragma unroll
      for (int j=0;j<4;++j) o[(size_t)(mb+j)*H_ + hc] = acc[tt][cc][j];
    }
  }
}

// ---------------- K7: merged reduce + bias + LeakyReLU over both outputs ----------------
__global__ void k_reduce(const float* __restrict__ partP, const float* __restrict__ partD,
    const float* __restrict__ bias, float* __restrict__ out){
  const int i = (blockIdx.x*256 + threadIdx.x)*4;
  float4 s; s.x=s.y=s.z=s.w=0.f;
  if (i < P_*H_){
    #pragma unroll
    for (int z = 0; z < 16; ++z){
      float4 v = *(const float4*)(partP + (size_t)z*((size_t)P_*H_) + i);
      s.x+=v.x; s.y+=v.y; s.z+=v.z; s.w+=v.w;
    }
  } else {
    const int j = i - P_*H_;
    #pragma unroll
    for (int z = 0; z < 8; ++z){
      float4 v = *(const float4*)(partD + (size_t)z*((size_t)D_*H_) + j);
      s.x+=v.x; s.y+=v.y; s.z+=v.z; s.w+=v.w;
    }
  }
  const float4 b = *(const float4*)(bias + (i & (H_-1)));
  s.x+=b.x; s.y+=b.y; s.z+=b.z; s.w+=b.w;
  s.x = (s.x>=0.f)? s.x : 0.1f*s.x;
  s.y = (s.y>=0.f)? s.y : 0.1f*s.y;
  s.z = (s.z>=0.f)? s.z : 0.1f*s.z;
  s.w = (s.w>=0.f)? s.w : 0.1f*s.w;
  *(float4*)(out + i) = s;
}

extern "C" void kernel_launch(void* const* d_in, const int* in_sizes, int n_in,
                              void* d_out, int out_size, void* d_ws, size_t ws_size,
                              hipStream_t stream){
  (void)in_sizes; (void)n_in; (void)out_size; (void)ws_size;
  const float* p_feat = (const float*)d_in[0];
  const float* d_feat = (const float*)d_in[1];
  const float* S      = (const float*)d_in[4];
  const float* pw     = (const float*)d_in[5];
  const float* bias   = (const float*)d_in[6];
  float* out = (float*)d_out;

  char* ws = (char*)d_ws;
  __bf16* wct    = (__bf16*)(ws + 0);           //  1,310,720
  __bf16* Tdt    = (__bf16*)(ws + 1310720);     // 10,485,760
  __bf16* Tpt    = (__bf16*)(ws + 11796480);    //  5,242,880
  float*  rs     = (float*) (ws + 17039360);    //     40,960
  float*  cs     = (float*) (ws + 17080320);    //     81,920
  float*  cspart = (float*) (ws + 17162240);    //  5,242,880 (64 slices)
  __bf16* Sbf    = (__bf16*)(ws + 22405120);    // 83,886,080
  float*  partP  = (float*) (ws + 106291200);   // 33,554,432 (16 slices)
  float*  partD  = (float*) (ws + 139845632);   // 33,554,432 (8 slices)
                                                // end: 173,400,064

  k_prep2 <<<384, 256, 0, stream>>>(S, pw, Sbf, rs, cspart, wct);
  k_csfin <<<(R_*D_)/256, 256, 0, stream>>>(cspart, cs);
  k_tmp   <<<dim3((P_+D_)/64, R_), 256, 0, stream>>>(p_feat, d_feat, rs, cs, wct, Tpt, Tdt);
  k_z     <<<512, 512, 0, stream>>>(Sbf, rs, cs, Tdt, Tpt, partP, partD);
  k_reduce<<<((P_+D_)*H_)/1024, 256, 0, stream>>>(partP, partD, bias, out);
}